// Round 15
// baseline (381.266 us; speedup 1.0000x reference)
//
#include <hip/hip_runtime.h>
#include <math.h>

#define NG 128
#define SEQ 512
#define NN 65536
#define EE 524288
#define DM 64
#define HSTR 80   // packed h row: 64 bf16 + 4 fp32 es + pad (160B stride)

typedef __attribute__((ext_vector_type(8))) short short8;
typedef __attribute__((ext_vector_type(4))) short short4v;
typedef __attribute__((ext_vector_type(4))) float f32x4;

__device__ __forceinline__ float lrelu(float x, float s){ return x > 0.f ? x : s*x; }

__device__ __forceinline__ unsigned short f2bf(float x){
  union { float f; unsigned u; } v; v.f = x;
  unsigned r = v.u + 0x7FFF + ((v.u>>16)&1);
  return (unsigned short)(r>>16);
}
__device__ __forceinline__ float bf2f(unsigned short x){
  union { unsigned u; float f; } v; v.u = ((unsigned)x)<<16;
  return v.f;
}

// ---------------- CSR build (by dst) ----------------
__global__ void k_count(const int* __restrict__ dst, int* __restrict__ deg){
  int e = blockIdx.x*256 + threadIdx.x;
  atomicAdd(&deg[dst[e]], 1);
}

__global__ void k_scan1(const int* __restrict__ deg, int* __restrict__ excl, int* __restrict__ bsums){
  __shared__ int sm[256];
  int tid = threadIdx.x;
  int i = blockIdx.x*256 + tid;
  int v = deg[i];
  sm[tid] = v;
  __syncthreads();
  int val = v;
  for (int off=1; off<256; off<<=1){
    int add = (tid>=off)? sm[tid-off] : 0;
    __syncthreads();
    val += add;
    sm[tid] = val;
    __syncthreads();
  }
  excl[i] = val - v;
  if (tid==255) bsums[blockIdx.x] = val;
}

__global__ void k_scan2(int* __restrict__ bsums){
  __shared__ int sm[256];
  int tid=threadIdx.x;
  int v = bsums[tid];
  sm[tid]=v;
  __syncthreads();
  int val=v;
  for (int off=1; off<256; off<<=1){
    int add = (tid>=off)? sm[tid-off]:0;
    __syncthreads();
    val += add;
    sm[tid]=val;
    __syncthreads();
  }
  bsums[tid] = val - v;
}

__global__ void k_scan3(const int* __restrict__ excl, const int* __restrict__ bsums,
                        int* __restrict__ rowp, int* __restrict__ cursor){
  int i = blockIdx.x*256 + threadIdx.x;
  int v = excl[i] + bsums[blockIdx.x];
  rowp[i]=v; cursor[i]=v;
  if (i==0) rowp[NN]=EE;
}

__global__ void k_fill(const int* __restrict__ src, const int* __restrict__ dst,
                       int* __restrict__ cursor, int* __restrict__ col){
  int e = blockIdx.x*256 + threadIdx.x;
  int d = dst[e];
  int p = atomicAdd(&cursor[d], 1);
  col[p] = src[e];
}

// ---------------- GAT0 transform: folds feature_fc, fp32 x input (DIN=4), packed output ----------------
__global__ void __launch_bounds__(256) k_transform0(const float* __restrict__ x,
                            const float* __restrict__ Wf, const float* __restrict__ bf,
                            const float* __restrict__ gW0,
                            const float* __restrict__ aSp, const float* __restrict__ aDp,
                            unsigned short* __restrict__ hout, float* __restrict__ ed){
  __shared__ float inL[4][68];
  __shared__ float Wl[4][64];
  __shared__ float b0l[64];
  __shared__ float asl[64], adl[64];
  int tid = threadIdx.x;
  int n0 = blockIdx.x*64;
  if (tid < 64){
    asl[tid] = aSp[tid]; adl[tid] = aDp[tid];
    float b = 0.f;
    #pragma unroll
    for (int k=0;k<4;k++) b += bf[k]*gW0[k*64+tid];
    b0l[tid] = b;
  }
  {
    int i = tid>>6, j = tid&63;
    float s = 0.f;
    #pragma unroll
    for (int k=0;k<4;k++) s += Wf[i*4+k]*gW0[k*64+j];
    Wl[i][j] = s;
  }
  if (tid < 64){
    float4 v = *(const float4*)&x[(size_t)(n0+tid)*4];
    inL[0][tid]=v.x; inL[1][tid]=v.y; inL[2][tid]=v.z; inL[3][tid]=v.w;
  }
  __syncthreads();
  int i = tid>>4, j = tid&15;
  float acc[4][4];
  #pragma unroll
  for (int r=0;r<4;r++){
    #pragma unroll
    for (int c=0;c<4;c++) acc[r][c] = 0.f;
  }
  #pragma unroll
  for (int k=0;k<4;k++){
    float4 av = *(float4*)&inL[k][4*i];
    float4 bv = *(float4*)&Wl[k][4*j];
    float a_[4]={av.x,av.y,av.z,av.w}, b_[4]={bv.x,bv.y,bv.z,bv.w};
    #pragma unroll
    for (int r=0;r<4;r++){
      #pragma unroll
      for (int c=0;c<4;c++) acc[r][c] += a_[r]*b_[c];
    }
  }
  float4 asv = *(float4*)&asl[4*j];
  float4 adv = *(float4*)&adl[4*j];
  float4 bbv = *(float4*)&b0l[4*j];
  float bb[4] = {bbv.x, bbv.y, bbv.z, bbv.w};
  #pragma unroll
  for (int r=0;r<4;r++){
    float y0=acc[r][0]+bb[0], y1=acc[r][1]+bb[1], y2=acc[r][2]+bb[2], y3=acc[r][3]+bb[3];
    int node = n0 + 4*i + r;
    ushort4 hv;
    hv.x=f2bf(y0); hv.y=f2bf(y1); hv.z=f2bf(y2); hv.w=f2bf(y3);
    *(ushort4*)&hout[(size_t)node*HSTR + 4*j] = hv;
    float ps = y0*asv.x + y1*asv.y + y2*asv.z + y3*asv.w;
    float pd = y0*adv.x + y1*adv.y + y2*adv.z + y3*adv.w;
    ps += __shfl_xor(ps,1); ps += __shfl_xor(ps,2);
    pd += __shfl_xor(pd,1); pd += __shfl_xor(pd,2);
    if ((j&3)==0){
      *(float*)&hout[(size_t)node*HSTR + 64 + 2*(j>>2)] = ps;
      ed[(size_t)node*4 + (j>>2)] = pd;
    }
  }
}

// ---------------- GAT transform (bf16 input), MFMA, packed output ----------------
__global__ void __launch_bounds__(256) k_transform_bf(const unsigned short* __restrict__ hin, const float* __restrict__ W,
                            const float* __restrict__ aSp, const float* __restrict__ aDp,
                            unsigned short* __restrict__ hout, float* __restrict__ ed){
  __shared__ __align__(16) char Ab[8192];
  __shared__ __align__(16) char Wt[8192];
  __shared__ float asl[64], adl[64];
  int tid = threadIdx.x;
  int n0 = blockIdx.x*64;
  if (tid < 64){ asl[tid]=aSp[tid]; adl[tid]=aDp[tid]; }
  #pragma unroll
  for (int it=0; it<2; it++){
    int idx = tid + it*256;
    int row = idx>>3, gr = idx&7;
    uint4 v = *(const uint4*)(hin + (size_t)(n0+row)*64 + gr*8);
    *(uint4*)(Ab + row*128 + ((gr*16) ^ ((row&7)<<4))) = v;
  }
  #pragma unroll
  for (int it=0; it<4; it++){
    int idx = tid + it*256;
    int k = idx>>4, c4 = (idx&15)<<2;
    float4 v = *(const float4*)(W + k*64 + c4);
    float vv[4]={v.x,v.y,v.z,v.w};
    #pragma unroll
    for (int c=0;c<4;c++){
      int col = c4+c;
      *(unsigned short*)(Wt + col*128 + ((2*k) ^ ((col&7)<<4))) = f2bf(vv[c]);
    }
  }
  __syncthreads();
  int wave = tid>>6, l=tid&63, lq=l&15, g4=l>>4;
  int nb = wave*16;
  const f32x4 zero = {0.f,0.f,0.f,0.f};
  short8 af[2];
  #pragma unroll
  for (int s=0;s<2;s++){
    int row = nb+lq;
    af[s] = *(short8*)(Ab + row*128 + (((s*64)+g4*16) ^ ((row&7)<<4)));
  }
  f32x4 acc[4];
  #pragma unroll
  for (int ct=0;ct<4;ct++){
    acc[ct]=zero;
    #pragma unroll
    for (int s=0;s<2;s++){
      int col = ct*16+lq;
      short8 wf = *(short8*)(Wt + col*128 + (((s*64)+g4*16) ^ ((col&7)<<4)));
      acc[ct] = __builtin_amdgcn_mfma_f32_16x16x32_bf16(af[s], wf, acc[ct], 0,0,0);
    }
  }
  #pragma unroll
  for (int ct=0;ct<4;ct++){
    float as_ = asl[ct*16+lq], ad_ = adl[ct*16+lq];
    #pragma unroll
    for (int r=0;r<4;r++){
      float y = acc[ct][r];
      int node = n0 + nb + 4*g4 + r;
      hout[(size_t)node*HSTR + ct*16 + lq] = f2bf(y);
      float ps = y*as_, pd = y*ad_;
      ps += __shfl_xor(ps,1); ps += __shfl_xor(ps,2); ps += __shfl_xor(ps,4); ps += __shfl_xor(ps,8);
      pd += __shfl_xor(pd,1); pd += __shfl_xor(pd,2); pd += __shfl_xor(pd,4); pd += __shfl_xor(pd,8);
      if (lq==0){
        *(float*)&hout[(size_t)node*HSTR + 64 + 2*ct] = ps;
        ed[(size_t)node*4 + ct] = pd;
      }
    }
  }
}

// ---------------- GAT aggregate: packed-row gather, scalar col loads ----------------
// MODE: 0 = fp32 out only, 1 = bf16 out only, 2 = both
template<int MODE>
__global__ void __launch_bounds__(256) k_aggregate(const unsigned short* __restrict__ h,
                            const float* __restrict__ ed, const int* __restrict__ rowp,
                            const int* __restrict__ col, const float* __restrict__ gb,
                            float* __restrict__ fout, unsigned short* __restrict__ bout){
  int tid = threadIdx.x;
  int n = blockIdx.x*4 + (tid>>6);
  int l = tid&63;
  int q = l>>4;
  int sl = l&15;
  int head = sl>>2;
  float edn = ed[(size_t)n*4 + head];
  float es_self = *(const float*)&h[(size_t)n*HSTR + 64 + 2*head];
  int beg = __builtin_amdgcn_readfirstlane(rowp[n]);
  int end = __builtin_amdgcn_readfirstlane(rowp[n+1]);
  float m = -1e30f, s = 0.f;
  float a0=0.f, a1=0.f, a2=0.f, a3=0.f;
  int i = beg;
  for (; i+8 <= end; i += 8){
    int c0=col[i], c1=col[i+1], c2=col[i+2], c3=col[i+3];
    int c4=col[i+4], c5=col[i+5], c6=col[i+6], c7=col[i+7];
    int t01 = (q&1)? c1 : c0;
    int t23 = (q&1)? c3 : c2;
    int sq0 = (q&2)? t23 : t01;
    int t45 = (q&1)? c5 : c4;
    int t67 = (q&1)? c7 : c6;
    int sq1 = (q&2)? t67 : t45;
    size_t b0r = (size_t)sq0*HSTR, b1r = (size_t)sq1*HSTR;
    ushort4 hv0 = *(const ushort4*)&h[b0r + 4*sl];
    ushort4 hv1 = *(const ushort4*)&h[b1r + 4*sl];
    float e0 = lrelu(*(const float*)&h[b0r + 64 + 2*head] + edn, 0.2f);
    float e1 = lrelu(*(const float*)&h[b1r + 64 + 2*head] + edn, 0.2f);
    float mx = fmaxf(e0, e1);
    if (__any(mx > m + 8.f)){
      float nm = fmaxf(m, mx);
      float c = __expf(m - nm);
      s*=c; a0*=c; a1*=c; a2*=c; a3*=c; m = nm;
    }
    float w0 = __expf(e0 - m);
    float w1 = __expf(e1 - m);
    s += w0 + w1;
    a0 += w0*bf2f(hv0.x) + w1*bf2f(hv1.x);
    a1 += w0*bf2f(hv0.y) + w1*bf2f(hv1.y);
    a2 += w0*bf2f(hv0.z) + w1*bf2f(hv1.z);
    a3 += w0*bf2f(hv0.w) + w1*bf2f(hv1.w);
  }
  if (i < end){
    int last = end-1;
    int i1=(i+1<last)?i+1:last, i2=(i+2<last)?i+2:last, i3=(i+3<last)?i+3:last;
    int i4=(i+4<last)?i+4:last, i5=(i+5<last)?i+5:last, i6=(i+6<last)?i+6:last;
    int c0=col[i], c1=col[i1], c2=col[i2], c3=col[i3];
    int c4=col[i4], c5=col[i5], c6=col[i6], c7=col[last];
    int t01 = (q&1)? c1 : c0;
    int t23 = (q&1)? c3 : c2;
    int sq0 = (q&2)? t23 : t01;
    int t45 = (q&1)? c5 : c4;
    int t67 = (q&1)? c7 : c6;
    int sq1 = (q&2)? t67 : t45;
    bool ac0 = (i + q) < end;
    bool ac1 = (i + 4 + q) < end;
    size_t b0r = (size_t)sq0*HSTR, b1r = (size_t)sq1*HSTR;
    ushort4 hv0 = *(const ushort4*)&h[b0r + 4*sl];
    ushort4 hv1 = *(const ushort4*)&h[b1r + 4*sl];
    float e0 = lrelu(*(const float*)&h[b0r + 64 + 2*head] + edn, 0.2f);
    float e1 = lrelu(*(const float*)&h[b1r + 64 + 2*head] + edn, 0.2f);
    if (!ac0) e0 = -1e30f;
    if (!ac1) e1 = -1e30f;
    float mx = fmaxf(e0, e1);
    if (__any(mx > m + 8.f)){
      float nm = fmaxf(m, mx);
      float c = __expf(m - nm);
      s*=c; a0*=c; a1*=c; a2*=c; a3*=c; m = nm;
    }
    float w0 = ac0 ? __expf(e0 - m) : 0.f;
    float w1 = ac1 ? __expf(e1 - m) : 0.f;
    s += w0 + w1;
    a0 += w0*bf2f(hv0.x) + w1*bf2f(hv1.x);
    a1 += w0*bf2f(hv0.y) + w1*bf2f(hv1.y);
    a2 += w0*bf2f(hv0.z) + w1*bf2f(hv1.z);
    a3 += w0*bf2f(hv0.w) + w1*bf2f(hv1.w);
  }
  #pragma unroll
  for (int off=16; off<=32; off<<=1){
    float m2 = __shfl_xor(m, off);
    float s2 = __shfl_xor(s, off);
    float b0 = __shfl_xor(a0, off);
    float b1 = __shfl_xor(a1, off);
    float b2 = __shfl_xor(a2, off);
    float b3 = __shfl_xor(a3, off);
    float nm = fmaxf(m, m2);
    float c1 = __expf(m - nm), c2 = __expf(m2 - nm);
    s  = s*c1  + s2*c2;
    a0 = a0*c1 + b0*c2;
    a1 = a1*c1 + b1*c2;
    a2 = a2*c1 + b2*c2;
    a3 = a3*c1 + b3*c2;
    m = nm;
  }
  {
    float e_self = lrelu(es_self + edn, 0.2f);
    float nm = fmaxf(m, e_self);
    float c = __expf(m - nm), cs = __expf(e_self - nm);
    ushort4 hs = *(const ushort4*)&h[(size_t)n*HSTR + 4*sl];
    s  = s*c  + cs;
    a0 = a0*c + cs*bf2f(hs.x);
    a1 = a1*c + cs*bf2f(hs.y);
    a2 = a2*c + cs*bf2f(hs.z);
    a3 = a3*c + cs*bf2f(hs.w);
  }
  if (q == 0){
    float inv = 1.f/(s + 1e-16f);
    float4 gv = *(const float4*)&gb[4*sl];
    float o0 = lrelu(a0*inv + gv.x, 0.01f);
    float o1 = lrelu(a1*inv + gv.y, 0.01f);
    float o2 = lrelu(a2*inv + gv.z, 0.01f);
    float o3 = lrelu(a3*inv + gv.w, 0.01f);
    if (MODE==0 || MODE==2){
      *(float4*)(fout + (size_t)n*64 + 4*sl) = make_float4(o0,o1,o2,o3);
    }
    if (MODE==1 || MODE==2){
      ushort4 hv; hv.x=f2bf(o0); hv.y=f2bf(o1); hv.z=f2bf(o2); hv.w=f2bf(o3);
      *(ushort4*)(bout + (size_t)n*64 + 4*sl) = hv;
    }
  }
}

// ---------------- triple linear via MFMA (bf16 inputs), bf16 outputs (scale on slot0) ----------------
__global__ void __launch_bounds__(256) k_qkv3(const unsigned short* __restrict__ in0, const float* __restrict__ W0, const float* __restrict__ b0, unsigned short* __restrict__ o0,
                      const unsigned short* __restrict__ in1, const float* __restrict__ W1, const float* __restrict__ b1, unsigned short* __restrict__ o1,
                      const unsigned short* __restrict__ in2, const float* __restrict__ W2, const float* __restrict__ b2, unsigned short* __restrict__ o2,
                      float scl0){
  __shared__ __align__(16) char Ab[8192];
  __shared__ __align__(16) char Wt[8192];
  int tid = threadIdx.x;
  int n0 = blockIdx.x*64;
  int wave = tid>>6, l=tid&63, lq=l&15, g4=l>>4;
  int nb = wave*16;
  const f32x4 zero = {0.f,0.f,0.f,0.f};
  const unsigned short* ins[3] = {in0, in1, in2};
  const float* Ws[3] = {W0, W1, W2};
  const float* bs[3] = {b0, b1, b2};
  unsigned short* os[3] = {o0, o1, o2};
  const unsigned short* cur = nullptr;
  short8 af[2];
  for (int w=0; w<3; w++){
    bool restage = (ins[w] != cur);
    __syncthreads();
    if (restage){
      cur = ins[w];
      #pragma unroll
      for (int it=0; it<2; it++){
        int idx = tid + it*256;
        int row = idx>>3, gr = idx&7;
        uint4 v = *(const uint4*)(cur + (size_t)(n0+row)*64 + gr*8);
        *(uint4*)(Ab + row*128 + ((gr*16) ^ ((row&7)<<4))) = v;
      }
    }
    #pragma unroll
    for (int it=0; it<4; it++){
      int idx = tid + it*256;
      int k = idx>>4, c4 = (idx&15)<<2;
      float4 v = *(const float4*)(Ws[w] + k*64 + c4);
      float vv[4]={v.x,v.y,v.z,v.w};
      #pragma unroll
      for (int c=0;c<4;c++){
        int colc = c4+c;
        *(unsigned short*)(Wt + colc*128 + ((2*k) ^ ((colc&7)<<4))) = f2bf(vv[c]);
      }
    }
    __syncthreads();
    if (restage){
      #pragma unroll
      for (int s=0;s<2;s++){
        int row = nb+lq;
        af[s] = *(short8*)(Ab + row*128 + (((s*64)+g4*16) ^ ((row&7)<<4)));
      }
    }
    float sc = (w==0) ? scl0 : 1.f;
    #pragma unroll
    for (int ct=0;ct<4;ct++){
      f32x4 acc = zero;
      #pragma unroll
      for (int s=0;s<2;s++){
        int colc = ct*16+lq;
        short8 wf = *(short8*)(Wt + colc*128 + (((s*64)+g4*16) ^ ((colc&7)<<4)));
        acc = __builtin_amdgcn_mfma_f32_16x16x32_bf16(af[s], wf, acc, 0,0,0);
      }
      float bv = bs[w][ct*16+lq];
      #pragma unroll
      for (int r=0;r<4;r++){
        int node = n0 + nb + 4*g4 + r;
        os[w][(size_t)node*64 + ct*16 + lq] = f2bf((acc[r] + bv)*sc);
      }
    }
  }
}

// ---------------- fused FFN via MFMA: out = LN(in + relu(in@W1+b1)@W2+b2) ----------------
__global__ void __launch_bounds__(256) k_ffn(const unsigned short* __restrict__ inb, const float* __restrict__ inf,
                     const float* __restrict__ W1p, const float* __restrict__ b1p,
                     const float* __restrict__ W2p, const float* __restrict__ b2p,
                     const float* __restrict__ g, const float* __restrict__ bl,
                     float* __restrict__ out){
  __shared__ __align__(16) char Ab[8192];
  __shared__ __align__(16) char Wt[8192];
  int tid = threadIdx.x;
  int n0 = blockIdx.x*64;
  int wave = tid>>6, l=tid&63, lq=l&15, g4=l>>4;
  int nb = wave*16;
  const f32x4 zero = {0.f,0.f,0.f,0.f};
  #pragma unroll
  for (int it=0; it<2; it++){
    int idx = tid + it*256;
    int row = idx>>3, gr = idx&7;
    uint4 v = *(const uint4*)(inb + (size_t)(n0+row)*64 + gr*8);
    *(uint4*)(Ab + row*128 + ((gr*16) ^ ((row&7)<<4))) = v;
  }
  #pragma unroll
  for (int it=0; it<4; it++){
    int idx = tid + it*256;
    int k = idx>>4, c4 = (idx&15)<<2;
    float4 v = *(const float4*)(W1p + k*64 + c4);
    float vv[4]={v.x,v.y,v.z,v.w};
    #pragma unroll
    for (int c=0;c<4;c++){
      int colc = c4+c;
      *(unsigned short*)(Wt + colc*128 + ((2*k) ^ ((colc&7)<<4))) = f2bf(vv[c]);
    }
  }
  __syncthreads();
  short8 af[2];
  #pragma unroll
  for (int s=0;s<2;s++){
    int row = nb+lq;
    af[s] = *(short8*)(Ab + row*128 + (((s*64)+g4*16) ^ ((row&7)<<4)));
  }
  #pragma unroll
  for (int ct=0;ct<4;ct++){
    f32x4 acc = zero;
    #pragma unroll
    for (int s=0;s<2;s++){
      int colc = ct*16+lq;
      short8 wf = *(short8*)(Wt + colc*128 + (((s*64)+g4*16) ^ ((colc&7)<<4)));
      acc = __builtin_amdgcn_mfma_f32_16x16x32_bf16(af[s], wf, acc, 0,0,0);
    }
    float bv = b1p[ct*16+lq];
    #pragma unroll
    for (int r=0;r<4;r++){
      int row = nb + 4*g4 + r;
      float y = fmaxf(acc[r] + bv, 0.f);
      *(unsigned short*)(Ab + row*128 + ((2*(ct*16+lq)) ^ ((row&7)<<4))) = f2bf(y);
    }
  }
  __syncthreads();
  #pragma unroll
  for (int it=0; it<4; it++){
    int idx = tid + it*256;
    int k = idx>>4, c4 = (idx&15)<<2;
    float4 v = *(const float4*)(W2p + k*64 + c4);
    float vv[4]={v.x,v.y,v.z,v.w};
    #pragma unroll
    for (int c=0;c<4;c++){
      int colc = c4+c;
      *(unsigned short*)(Wt + colc*128 + ((2*k) ^ ((colc&7)<<4))) = f2bf(vv[c]);
    }
  }
  __syncthreads();
  #pragma unroll
  for (int s=0;s<2;s++){
    int row = nb+lq;
    af[s] = *(short8*)(Ab + row*128 + (((s*64)+g4*16) ^ ((row&7)<<4)));
  }
  float yv[4][4];
  #pragma unroll
  for (int ct=0;ct<4;ct++){
    f32x4 acc = zero;
    #pragma unroll
    for (int s=0;s<2;s++){
      int colc = ct*16+lq;
      short8 wf = *(short8*)(Wt + colc*128 + (((s*64)+g4*16) ^ ((colc&7)<<4)));
      acc = __builtin_amdgcn_mfma_f32_16x16x32_bf16(af[s], wf, acc, 0,0,0);
    }
    float bv = b2p[ct*16+lq];
    #pragma unroll
    for (int r=0;r<4;r++){
      int node = n0 + nb + 4*g4 + r;
      yv[ct][r] = acc[r] + bv + inf[(size_t)node*64 + ct*16 + lq];
    }
  }
  float gg[4], bbl[4];
  #pragma unroll
  for (int ct=0;ct<4;ct++){ gg[ct]=g[ct*16+lq]; bbl[ct]=bl[ct*16+lq]; }
  #pragma unroll
  for (int r=0;r<4;r++){
    int node = n0 + nb + 4*g4 + r;
    float s = (yv[0][r]+yv[1][r]) + (yv[2][r]+yv[3][r]);
    s += __shfl_xor(s,1); s += __shfl_xor(s,2); s += __shfl_xor(s,4); s += __shfl_xor(s,8);
    float mean = s * (1.f/64.f);
    float d[4];
    #pragma unroll
    for (int ct=0;ct<4;ct++) d[ct] = yv[ct][r] - mean;
    float v = (d[0]*d[0]+d[1]*d[1]) + (d[2]*d[2]+d[3]*d[3]);
    v += __shfl_xor(v,1); v += __shfl_xor(v,2); v += __shfl_xor(v,4); v += __shfl_xor(v,8);
    float inv = rsqrtf(v*(1.f/64.f) + 1e-5f);
    #pragma unroll
    for (int ct=0;ct<4;ct++){
      out[(size_t)node*64 + ct*16 + lq] = d[ct]*inv*gg[ct] + bbl[ct];
    }
  }
}

// ---------------- MFMA flash attention + fused out-proj/residual/LN, v6 ----------------
// round-13 schedule (NG*4 x 512 thr) + log2e folded into Q scale -> exp2f softmax.
__global__ void __launch_bounds__(512) k_attn_fused(const unsigned short* __restrict__ Q, const unsigned short* __restrict__ K,
                      const unsigned short* __restrict__ V,
                      const float* __restrict__ Wo, const float* __restrict__ bo,
                      const float* __restrict__ res, const float* __restrict__ g, const float* __restrict__ bl,
                      float* __restrict__ out, unsigned short* __restrict__ outb){
  __shared__ __align__(16) char smem[49152];
  char* Ksm = smem;          // [128 keys][128B both heads], granule XOR swizzle ((row&7)<<4)
  char* Vsm = smem + 16384;  // V^T [64 dims][256B keys], swizzle ((d&7)^(d>>3&7))<<4
  char* Psm = smem + 32768;  // per-wave 2KB: P [16 q][128B keys], swizzle ((lq&7)<<4)

  int bid = blockIdx.x;
  int qq = bid & 3;
  int b  = bid >> 2;
  int tid = threadIdx.x;
  int wave = tid>>6;
  int l = tid & 63;
  int lq = l & 15;
  int g4 = l >> 4;
  int head = wave & 1;
  int qg = wave >> 1;           // 0..3
  const size_t gb = (size_t)b*SEQ*64;
  const int hoff = head*32;
  const f32x4 zero = {0.f,0.f,0.f,0.f};

  int qrow0 = qq*128 + qg*32;
  short8 qf[2];
  f32x4 O[2][2];
  float m_[2], l_[2];
  #pragma unroll
  for (int qt=0; qt<2; qt++){
    qf[qt] = *(const short8*)(Q + gb + (size_t)(qrow0 + qt*16 + lq)*64 + hoff + g4*8);
    O[qt][0] = zero; O[qt][1] = zero;
    m_[qt] = -1e30f; l_[qt] = 0.f;
  }
  char* Pw = Psm + wave*2048;
  int swzp = (lq&7)<<4;
  int d0 = hoff + lq, d1 = hoff + lq + 16;
  int sv0 = (((d0&7) ^ ((d0>>3)&7)) << 4);
  int sv1 = (((d1&7) ^ ((d1>>3)&7)) << 4);

  for (int ph=0; ph<4; ph++){
    __syncthreads();
    #pragma unroll
    for (int it=0; it<2; it++){
      int idx = tid + it*512;
      int row = idx>>3, gr = idx&7;
      uint4 v = *(const uint4*)(K + gb + (size_t)(ph*128 + row)*64 + gr*8);
      *(uint4*)(Ksm + row*128 + ((gr*16) ^ ((row&7)<<4))) = v;
    }
    #pragma unroll
    for (int it=0; it<2; it++){
      int idx = tid + it*512;
      int key = idx>>3, gr = idx&7;
      uint4 vv = *(const uint4*)(V + gb + (size_t)(ph*128 + key)*64 + gr*8);
      const unsigned short* vs = (const unsigned short*)&vv;
      #pragma unroll
      for (int c=0;c<8;c++){
        int d = gr*8 + c;
        int swz = ((c ^ gr) & 7) << 4;
        *(unsigned short*)(Vsm + d*256 + ((key*2) ^ swz)) = vs[c];
      }
    }
    __syncthreads();
    for (int p2=0; p2<2; p2++){
      int rb = p2*64 + lq;
      short8 kf0 = *(short8*)(Ksm + rb*128      + ((hoff*2 + g4*16) ^ ((rb&7)<<4)));
      short8 kf1 = *(short8*)(Ksm + (rb+16)*128 + ((hoff*2 + g4*16) ^ (((rb+16)&7)<<4)));
      short8 kf2 = *(short8*)(Ksm + (rb+32)*128 + ((hoff*2 + g4*16) ^ (((rb+32)&7)<<4)));
      short8 kf3 = *(short8*)(Ksm + (rb+48)*128 + ((hoff*2 + g4*16) ^ (((rb+48)&7)<<4)));
      short8 vt00 = *(short8*)(Vsm + d0*256 + ((p2*128 + g4*16) ^ sv0));
      short8 vt01 = *(short8*)(Vsm + d0*256 + ((p2*128 + 64 + g4*16) ^ sv0));
      short8 vt10 = *(short8*)(Vsm + d1*256 + ((p2*128 + g4*16) ^ sv1));
      short8 vt11 = *(short8*)(Vsm + d1*256 + ((p2*128 + 64 + g4*16) ^ sv1));
      #pragma unroll
      for (int qt=0; qt<2; qt++){
        f32x4 s0 = __builtin_amdgcn_mfma_f32_16x16x32_bf16(kf0, qf[qt], zero, 0,0,0);
        f32x4 s1 = __builtin_amdgcn_mfma_f32_16x16x32_bf16(kf1, qf[qt], zero, 0,0,0);
        f32x4 s2 = __builtin_amdgcn_mfma_f32_16x16x32_bf16(kf2, qf[qt], zero, 0,0,0);
        f32x4 s3 = __builtin_amdgcn_mfma_f32_16x16x32_bf16(kf3, qf[qt], zero, 0,0,0);
        float pmax = fmaxf(
          fmaxf(fmaxf(fmaxf(s0.x,s0.y),fmaxf(s0.z,s0.w)), fmaxf(fmaxf(s1.x,s1.y),fmaxf(s1.z,s1.w))),
          fmaxf(fmaxf(fmaxf(s2.x,s2.y),fmaxf(s2.z,s2.w)), fmaxf(fmaxf(s3.x,s3.y),fmaxf(s3.z,s3.w))));
        pmax = fmaxf(pmax, __shfl_xor(pmax, 16));
        pmax = fmaxf(pmax, __shfl_xor(pmax, 32));
        if (__any(pmax > m_[qt] + 8.f)){       // defer-max: 2^8 headroom
          float mn = fmaxf(m_[qt], pmax);
          float corr = exp2f(m_[qt] - mn);
          l_[qt] *= corr;
          O[qt][0] *= corr; O[qt][1] *= corr;
          m_[qt] = mn;
        }
        float mm = m_[qt];
        float e0 = exp2f(s0.x - mm), e1 = exp2f(s0.y - mm);
        float e2 = exp2f(s0.z - mm), e3 = exp2f(s0.w - mm);
        float e4 = exp2f(s1.x - mm), e5 = exp2f(s1.y - mm);
        float e6 = exp2f(s1.z - mm), e7 = exp2f(s1.w - mm);
        float e8 = exp2f(s2.x - mm), e9 = exp2f(s2.y - mm);
        float ea = exp2f(s2.z - mm), eb = exp2f(s2.w - mm);
        float ec = exp2f(s3.x - mm), ed_ = exp2f(s3.y - mm);
        float ee = exp2f(s3.z - mm), ef = exp2f(s3.w - mm);
        l_[qt] += (((e0+e1)+(e2+e3)) + ((e4+e5)+(e6+e7)))
                + (((e8+e9)+(ea+eb)) + ((ec+ed_)+(ee+ef)));
        uint2 w0, w1, w2, w3;
        w0.x = (unsigned)f2bf(e0) | ((unsigned)f2bf(e1)<<16);
        w0.y = (unsigned)f2bf(e2) | ((unsigned)f2bf(e3)<<16);
        w1.x = (unsigned)f2bf(e4) | ((unsigned)f2bf(e5)<<16);
        w1.y = (unsigned)f2bf(e6) | ((unsigned)f2bf(e7)<<16);
        w2.x = (unsigned)f2bf(e8) | ((unsigned)f2bf(e9)<<16);
        w2.y = (unsigned)f2bf(ea) | ((unsigned)f2bf(eb)<<16);
        w3.x = (unsigned)f2bf(ec) | ((unsigned)f2bf(ed_)<<16);
        w3.y = (unsigned)f2bf(ee) | ((unsigned)f2bf(ef)<<16);
        *(uint2*)(Pw + lq*128 + ((g4*8) ^ swzp))      = w0;
        *(uint2*)(Pw + lq*128 + ((32 + g4*8) ^ swzp)) = w1;
        *(uint2*)(Pw + lq*128 + ((64 + g4*8) ^ swzp)) = w2;
        *(uint2*)(Pw + lq*128 + ((96 + g4*8) ^ swzp)) = w3;
        short8 pb0 = *(short8*)(Pw + lq*128 + ((g4*16) ^ swzp));
        short8 pb1 = *(short8*)(Pw + lq*128 + ((64 + g4*16) ^ swzp));
        O[qt][0] = __builtin_amdgcn_mfma_f32_16x16x32_bf16(vt00, pb0, O[qt][0], 0,0,0);
        O[qt][0] = __builtin_amdgcn_mfma_f32_16x16x32_bf16(vt01, pb1, O[qt][0], 0,0,0);
        O[qt][1] = __builtin_amdgcn_mfma_f32_16x16x32_bf16(vt10, pb0, O[qt][1], 0,0,0);
        O[qt][1] = __builtin_amdgcn_mfma_f32_16x16x32_bf16(vt11, pb1, O[qt][1], 0,0,0);
      }
    }
  }
  // ---- epilogue: O^T to LDS (bf16 [64][136]), then out-proj + residual + LN ----
  __syncthreads();
  unsigned short* OT = (unsigned short*)smem;           // [64 dims][136 rows]
  float* WoL = (float*)(smem + 17664);                  // [64][64]
  #pragma unroll
  for (int qt=0; qt<2; qt++){
    float lt = l_[qt];
    lt += __shfl_xor(lt, 16);
    lt += __shfl_xor(lt, 32);
    float inv = 1.f/lt;
    int row = qg*32 + qt*16 + lq;
    #pragma unroll
    for (int c=0;c<4;c++){
      OT[(hoff + g4*4 + c)*136 + row]      = f2bf(O[qt][0][c]*inv);
      OT[(hoff + 16 + g4*4 + c)*136 + row] = f2bf(O[qt][1][c]*inv);
    }
  }
  for (int idx=tid; idx<1024; idx+=512){
    int k = idx>>4, jj = (idx&15)<<2;
    *(float4*)&WoL[k*64+jj] = *(const float4*)&Wo[k*64+jj];
  }
  __syncthreads();
  int i = tid>>4, j = tid&15;
  float acc[4][4];
  #pragma unroll
  for (int r=0;r<4;r++){
    #pragma unroll
    for (int c=0;c<4;c++) acc[r][c] = 0.f;
  }
  #pragma unroll 4
  for (int k=0;k<64;k++){
    short4v av = *(short4v*)&OT[k*136 + 4*i];
    float4 bv = *(float4*)&WoL[k*64 + 4*j];
    float b_[4]={bv.x,bv.y,bv.z,bv.w};
    #pragma unroll
    for (int r=0;r<4;r++){
      float a = bf2f((unsigned short)av[r]);
      #pragma unroll
      for (int c=0;c<4;c++) acc[r][c] += a*b_[c];
    }
  }
  float4 bov = *(const float4*)&bo[4*j];
  float4 gv = *(const float4*)&g[4*j];
  float4 blv = *(const float4*)&bl[4*j];
  float bb[4] = {bov.x, bov.y, bov.z, bov.w};
  float gg[4] = {gv.x, gv.y, gv.z, gv.w};
  float bbl[4] = {blv.x, blv.y, blv.z, blv.w};
  #pragma unroll
  for (int r=0;r<4;r++){
    int row = 4*i + r;
    int node = b*SEQ + qq*128 + row;
    float4 rv = *(const float4*)&res[(size_t)node*64 + 4*j];
    float y[4] = {acc[r][0]+bb[0]+rv.x, acc[r][1]+bb[1]+rv.y,
                  acc[r][2]+bb[2]+rv.z, acc[r][3]+bb[3]+rv.w};
    float s = (y[0]+y[1]) + (y[2]+y[3]);
    s += __shfl_xor(s,1); s += __shfl_xor(s,2); s += __shfl_xor(s,4); s += __shfl_xor(s,8);
    float mean = s * (1.f/64.f);
    float d[4] = {y[0]-mean, y[1]-mean, y[2]-mean, y[3]-mean};
    float v = (d[0]*d[0]+d[1]*d[1]) + (d[2]*d[2]+d[3]*d[3]);
    v += __shfl_xor(v,1); v += __shfl_xor(v,2); v += __shfl_xor(v,4); v += __shfl_xor(v,8);
    float inv = rsqrtf(v*(1.f/64.f) + 1e-5f);
    float o0 = d[0]*inv*gg[0]+bbl[0];
    float o1 = d[1]*inv*gg[1]+bbl[1];
    float o2 = d[2]*inv*gg[2]+bbl[2];
    float o3 = d[3]*inv*gg[3]+bbl[3];
    *(float4*)&out[(size_t)node*64 + 4*j] = make_float4(o0,o1,o2,o3);
    ushort4 ob; ob.x=f2bf(o0); ob.y=f2bf(o1); ob.z=f2bf(o2); ob.w=f2bf(o3);
    *(ushort4*)&outb[(size_t)node*64 + 4*j] = ob;
  }
}

// ---------------- mean-pool over 512 nodes + final fc ----------------
__global__ void __launch_bounds__(256) k_pool_fc(const float* __restrict__ t, const float* __restrict__ fcW,
                          const float* __restrict__ fcb, float* __restrict__ out){
  __shared__ float pl[4][64];
  __shared__ float pf[64];
  int b = blockIdx.x;
  int tid = threadIdx.x;
  int j = tid&63, seg = tid>>6;
  const float* basep = t + (size_t)b*SEQ*64;
  float s = 0.f;
  for (int si=seg*128; si<(seg+1)*128; si++) s += basep[(size_t)si*64 + j];
  pl[seg][j] = s;
  __syncthreads();
  if (tid < 64){
    pf[tid] = (pl[0][tid]+pl[1][tid]+pl[2][tid]+pl[3][tid]) * (1.f/512.f);
  }
  __syncthreads();
  if (tid < 64){
    float o = fcb[tid];
    for (int k=0;k<64;k++) o += pf[k]*fcW[k*64+tid];
    out[(size_t)b*64 + tid] = o;
  }
}

extern "C" void kernel_launch(void* const* d_in, const int* in_sizes, int n_in,
                              void* d_out, int out_size, void* d_ws, size_t ws_size,
                              hipStream_t stream) {
  const float* x    = (const float*)d_in[0];
  const int*   ei   = (const int*)d_in[1];      // [2,E]: src row 0, dst row 1
  const float* Wf   = (const float*)d_in[3];
  const float* bf   = (const float*)d_in[4];
  const float* gW0  = (const float*)d_in[5];
  const float* aS0  = (const float*)d_in[6];
  const float* aD0  = (const float*)d_in[7];
  const float* gb0  = (const float*)d_in[8];
  const float* gW   = (const float*)d_in[9];
  const float* aS   = (const float*)d_in[10];
  const float* aD   = (const float*)d_in[11];
  const float* gb   = (const float*)d_in[12];
  const float* sWq  = (const float*)d_in[13];
  const float* sWk  = (const float*)d_in[14];
  const float* sWv  = (const float*)d_in[15];
  const float* sWo  = (const float*)d_in[16];
  const float* cWq  = (const float*)d_in[17];
  const float* cWk  = (const float*)d_in[18];
  const float* cWv  = (const float*)d_in[19];
  const float* cWo  = (const float*)d_in[20];
  const float* sbq  = (const float*)d_in[21];
  const float* sbk  = (const float*)d_in[22];
  const float* sbv  = (const float*)d_in[23];
  const float* sbo  = (const float*)d_in[24];
  const float* cbq  = (const float*)d_in[25];
  const float* cbk  = (const float*)d_in[26];
  const float* cbv  = (const float*)d_in[27];
  const float* cbo  = (const float*)d_in[28];
  const float* ln1g = (const float*)d_in[29];
  const float* ln1b = (const float*)d_in[30];
  const float* ln2g = (const float*)d_in[31];
  const float* ln2b = (const float*)d_in[32];
  const float* ln3g = (const float*)d_in[33];
  const float* ln3b = (const float*)d_in[34];
  const float* ffW1 = (const float*)d_in[35];
  const float* ffb1 = (const float*)d_in[36];
  const float* ffW2 = (const float*)d_in[37];
  const float* ffb2 = (const float*)d_in[38];
  const float* fcW  = (const float*)d_in[39];
  const float* fcb  = (const float*)d_in[40];

  char* ws = (char*)d_ws;
  size_t off = 0;
  auto alloc = [&](size_t bytes) -> void* {
    void* p = ws + off;
    off += (bytes + 255) & ~(size_t)255;
    return p;
  };
  int* deg    = (int*)alloc(NN*sizeof(int));
  int* excl   = (int*)alloc(NN*sizeof(int));
  int* rowp   = (int*)alloc((NN+1)*sizeof(int));
  int* cursor = (int*)alloc(NN*sizeof(int));
  int* col    = (int*)alloc(EE*sizeof(int));
  int* bsums  = (int*)alloc(256*sizeof(int));
  float* ed   = (float*)alloc((size_t)NN*4*sizeof(float));
  unsigned short* Hb   = (unsigned short*)alloc((size_t)NN*HSTR*sizeof(unsigned short));
  unsigned short* Hagg = (unsigned short*)alloc((size_t)NN*64*sizeof(unsigned short));
  unsigned short* Qb  = (unsigned short*)alloc((size_t)NN*64*sizeof(unsigned short));
  unsigned short* Kb  = (unsigned short*)alloc((size_t)NN*64*sizeof(unsigned short));
  unsigned short* Vb  = (unsigned short*)alloc((size_t)NN*64*sizeof(unsigned short));
  unsigned short* B5b = (unsigned short*)alloc((size_t)NN*64*sizeof(unsigned short));
  unsigned short* B2b = (unsigned short*)alloc((size_t)NN*64*sizeof(unsigned short));
  float* B1   = (float*)alloc((size_t)NN*64*sizeof(float));
  float* B2   = (float*)alloc((size_t)NN*64*sizeof(float));
  float* B5   = (float*)alloc((size_t)NN*64*sizeof(float));

  const int* e_src = ei;
  const int* e_dst = ei + EE;

  const float scale = 0.2550348424f; // (1/sqrt(32)) * log2(e): exp2-domain softmax

  // CSR build
  hipMemsetAsync(deg, 0, NN*sizeof(int), stream);
  k_count<<<EE/256, 256, 0, stream>>>(e_dst, deg);
  k_scan1<<<NN/256, 256, 0, stream>>>(deg, excl, bsums);
  k_scan2<<<1, 256, 0, stream>>>(bsums);
  k_scan3<<<NN/256, 256, 0, stream>>>(excl, bsums, rowp, cursor);
  k_fill<<<EE/256, 256, 0, stream>>>(e_src, e_dst, cursor, col);

  // GAT0: x -> Hb (packed bf16+es) -> Hagg (bf16)
  k_transform0<<<NN/64, 256, 0, stream>>>(x, Wf, bf, gW0, aS0, aD0, Hb, ed);
  k_aggregate<1><<<NN/4, 256, 0, stream>>>(Hb, ed, rowp, col, gb0, nullptr, Hagg);
  // GAT1
  k_transform_bf<<<NN/64, 256, 0, stream>>>(Hagg, gW+0*4096, aS+0*64, aD+0*64, Hb, ed);
  k_aggregate<1><<<NN/4, 256, 0, stream>>>(Hb, ed, rowp, col, gb+0*64, nullptr, Hagg);
  // GAT2
  k_transform_bf<<<NN/64, 256, 0, stream>>>(Hagg, gW+1*4096, aS+1*64, aD+1*64, Hb, ed);
  k_aggregate<1><<<NN/4, 256, 0, stream>>>(Hb, ed, rowp, col, gb+1*64, nullptr, Hagg);
  // GAT3 -> B2 (fp32, residual/mem) + Hagg (bf16 copy, decoder GEMM input)
  k_transform_bf<<<NN/64, 256, 0, stream>>>(Hagg, gW+2*4096, aS+2*64, aD+2*64, Hb, ed);
  k_aggregate<2><<<NN/4, 256, 0, stream>>>(Hb, ed, rowp, col, gb+2*64, B2, Hagg);

  // self-attention: Qb/Kb/Vb from bf16 Hagg; fused attn+proj+res+LN -> B5 (+B5b)
  k_qkv3<<<NN/64, 256, 0, stream>>>(Hagg, sWq, sbq, Qb, Hagg, sWk, sbk, Kb, Hagg, sWv, sbv, Vb, scale);
  k_attn_fused<<<NG*4, 512, 0, stream>>>(Qb, Kb, Vb, sWo, sbo, B2, ln1g, ln1b, B5, B5b);

  // cross-attention: Q from B5b (t1), K/V from Hagg (mem); fused -> B2 (+B2b)
  k_qkv3<<<NN/64, 256, 0, stream>>>(B5b, cWq, cbq, Qb, Hagg, cWk, cbk, Kb, Hagg, cWv, cbv, Vb, scale);
  k_attn_fused<<<NG*4, 512, 0, stream>>>(Qb, Kb, Vb, cWo, cbo, B5, ln2g, ln2b, B2, B2b);

  // fused FFN via MFMA: t3 = LN(t2 + relu(t2@ffW1+ffb1)@ffW2+ffb2) -> B1
  k_ffn<<<NN/64, 256, 0, stream>>>(B2b, B2, ffW1, ffb1, ffW2, ffb2, ln3g, ln3b, B1);

  // pool + fc
  k_pool_fc<<<NG, 256, 0, stream>>>(B1, fcW, fcb, (float*)d_out);
}

// Round 16
// 367.813 us; speedup vs baseline: 1.0366x; 1.0366x over previous
//
#include <hip/hip_runtime.h>
#include <math.h>

#define NG 128
#define SEQ 512
#define NN 65536
#define EE 524288
#define DM 64
#define HSTR 80   // packed h row: 64 bf16 + 4 fp32 es + pad (160B stride)

typedef __attribute__((ext_vector_type(8))) short short8;
typedef __attribute__((ext_vector_type(4))) short short4v;
typedef __attribute__((ext_vector_type(4))) float f32x4;

__device__ __forceinline__ float lrelu(float x, float s){ return x > 0.f ? x : s*x; }

__device__ __forceinline__ unsigned short f2bf(float x){
  union { float f; unsigned u; } v; v.f = x;
  unsigned r = v.u + 0x7FFF + ((v.u>>16)&1);
  return (unsigned short)(r>>16);
}
__device__ __forceinline__ float bf2f(unsigned short x){
  union { unsigned u; float f; } v; v.u = ((unsigned)x)<<16;
  return v.f;
}

// ---------------- CSR build (by dst) ----------------
__global__ void k_count(const int* __restrict__ dst, int* __restrict__ deg){
  int e = blockIdx.x*256 + threadIdx.x;
  atomicAdd(&deg[dst[e]], 1);
}

__global__ void k_scan1(const int* __restrict__ deg, int* __restrict__ excl, int* __restrict__ bsums){
  __shared__ int sm[256];
  int tid = threadIdx.x;
  int i = blockIdx.x*256 + tid;
  int v = deg[i];
  sm[tid] = v;
  __syncthreads();
  int val = v;
  for (int off=1; off<256; off<<=1){
    int add = (tid>=off)? sm[tid-off] : 0;
    __syncthreads();
    val += add;
    sm[tid] = val;
    __syncthreads();
  }
  excl[i] = val - v;
  if (tid==255) bsums[blockIdx.x] = val;
}

__global__ void k_scan2(int* __restrict__ bsums){
  __shared__ int sm[256];
  int tid=threadIdx.x;
  int v = bsums[tid];
  sm[tid]=v;
  __syncthreads();
  int val=v;
  for (int off=1; off<256; off<<=1){
    int add = (tid>=off)? sm[tid-off]:0;
    __syncthreads();
    val += add;
    sm[tid]=val;
    __syncthreads();
  }
  bsums[tid] = val - v;
}

__global__ void k_scan3(const int* __restrict__ excl, const int* __restrict__ bsums,
                        int* __restrict__ rowp, int* __restrict__ cursor){
  int i = blockIdx.x*256 + threadIdx.x;
  int v = excl[i] + bsums[blockIdx.x];
  rowp[i]=v; cursor[i]=v;
  if (i==0) rowp[NN]=EE;
}

__global__ void k_fill(const int* __restrict__ src, const int* __restrict__ dst,
                       int* __restrict__ cursor, int* __restrict__ col){
  int e = blockIdx.x*256 + threadIdx.x;
  int d = dst[e];
  int p = atomicAdd(&cursor[d], 1);
  col[p] = src[e];
}

// ---------------- GAT0 transform: folds feature_fc, fp32 x input (DIN=4), packed output ----------------
__global__ void __launch_bounds__(256) k_transform0(const float* __restrict__ x,
                            const float* __restrict__ Wf, const float* __restrict__ bf,
                            const float* __restrict__ gW0,
                            const float* __restrict__ aSp, const float* __restrict__ aDp,
                            unsigned short* __restrict__ hout, float* __restrict__ ed){
  __shared__ float inL[4][68];
  __shared__ float Wl[4][64];
  __shared__ float b0l[64];
  __shared__ float asl[64], adl[64];
  int tid = threadIdx.x;
  int n0 = blockIdx.x*64;
  if (tid < 64){
    asl[tid] = aSp[tid]; adl[tid] = aDp[tid];
    float b = 0.f;
    #pragma unroll
    for (int k=0;k<4;k++) b += bf[k]*gW0[k*64+tid];
    b0l[tid] = b;
  }
  {
    int i = tid>>6, j = tid&63;
    float s = 0.f;
    #pragma unroll
    for (int k=0;k<4;k++) s += Wf[i*4+k]*gW0[k*64+j];
    Wl[i][j] = s;
  }
  if (tid < 64){
    float4 v = *(const float4*)&x[(size_t)(n0+tid)*4];
    inL[0][tid]=v.x; inL[1][tid]=v.y; inL[2][tid]=v.z; inL[3][tid]=v.w;
  }
  __syncthreads();
  int i = tid>>4, j = tid&15;
  float acc[4][4];
  #pragma unroll
  for (int r=0;r<4;r++){
    #pragma unroll
    for (int c=0;c<4;c++) acc[r][c] = 0.f;
  }
  #pragma unroll
  for (int k=0;k<4;k++){
    float4 av = *(float4*)&inL[k][4*i];
    float4 bv = *(float4*)&Wl[k][4*j];
    float a_[4]={av.x,av.y,av.z,av.w}, b_[4]={bv.x,bv.y,bv.z,bv.w};
    #pragma unroll
    for (int r=0;r<4;r++){
      #pragma unroll
      for (int c=0;c<4;c++) acc[r][c] += a_[r]*b_[c];
    }
  }
  float4 asv = *(float4*)&asl[4*j];
  float4 adv = *(float4*)&adl[4*j];
  float4 bbv = *(float4*)&b0l[4*j];
  float bb[4] = {bbv.x, bbv.y, bbv.z, bbv.w};
  #pragma unroll
  for (int r=0;r<4;r++){
    float y0=acc[r][0]+bb[0], y1=acc[r][1]+bb[1], y2=acc[r][2]+bb[2], y3=acc[r][3]+bb[3];
    int node = n0 + 4*i + r;
    ushort4 hv;
    hv.x=f2bf(y0); hv.y=f2bf(y1); hv.z=f2bf(y2); hv.w=f2bf(y3);
    *(ushort4*)&hout[(size_t)node*HSTR + 4*j] = hv;
    float ps = y0*asv.x + y1*asv.y + y2*asv.z + y3*asv.w;
    float pd = y0*adv.x + y1*adv.y + y2*adv.z + y3*adv.w;
    ps += __shfl_xor(ps,1); ps += __shfl_xor(ps,2);
    pd += __shfl_xor(pd,1); pd += __shfl_xor(pd,2);
    if ((j&3)==0){
      *(float*)&hout[(size_t)node*HSTR + 64 + 2*(j>>2)] = ps;
      ed[(size_t)node*4 + (j>>2)] = pd;
    }
  }
}

// ---------------- GAT transform (bf16 input), MFMA, packed output ----------------
__global__ void __launch_bounds__(256) k_transform_bf(const unsigned short* __restrict__ hin, const float* __restrict__ W,
                            const float* __restrict__ aSp, const float* __restrict__ aDp,
                            unsigned short* __restrict__ hout, float* __restrict__ ed){
  __shared__ __align__(16) char Ab[8192];
  __shared__ __align__(16) char Wt[8192];
  __shared__ float asl[64], adl[64];
  int tid = threadIdx.x;
  int n0 = blockIdx.x*64;
  if (tid < 64){ asl[tid]=aSp[tid]; adl[tid]=aDp[tid]; }
  #pragma unroll
  for (int it=0; it<2; it++){
    int idx = tid + it*256;
    int row = idx>>3, gr = idx&7;
    uint4 v = *(const uint4*)(hin + (size_t)(n0+row)*64 + gr*8);
    *(uint4*)(Ab + row*128 + ((gr*16) ^ ((row&7)<<4))) = v;
  }
  #pragma unroll
  for (int it=0; it<4; it++){
    int idx = tid + it*256;
    int k = idx>>4, c4 = (idx&15)<<2;
    float4 v = *(const float4*)(W + k*64 + c4);
    float vv[4]={v.x,v.y,v.z,v.w};
    #pragma unroll
    for (int c=0;c<4;c++){
      int col = c4+c;
      *(unsigned short*)(Wt + col*128 + ((2*k) ^ ((col&7)<<4))) = f2bf(vv[c]);
    }
  }
  __syncthreads();
  int wave = tid>>6, l=tid&63, lq=l&15, g4=l>>4;
  int nb = wave*16;
  const f32x4 zero = {0.f,0.f,0.f,0.f};
  short8 af[2];
  #pragma unroll
  for (int s=0;s<2;s++){
    int row = nb+lq;
    af[s] = *(short8*)(Ab + row*128 + (((s*64)+g4*16) ^ ((row&7)<<4)));
  }
  f32x4 acc[4];
  #pragma unroll
  for (int ct=0;ct<4;ct++){
    acc[ct]=zero;
    #pragma unroll
    for (int s=0;s<2;s++){
      int col = ct*16+lq;
      short8 wf = *(short8*)(Wt + col*128 + (((s*64)+g4*16) ^ ((col&7)<<4)));
      acc[ct] = __builtin_amdgcn_mfma_f32_16x16x32_bf16(af[s], wf, acc[ct], 0,0,0);
    }
  }
  #pragma unroll
  for (int ct=0;ct<4;ct++){
    float as_ = asl[ct*16+lq], ad_ = adl[ct*16+lq];
    #pragma unroll
    for (int r=0;r<4;r++){
      float y = acc[ct][r];
      int node = n0 + nb + 4*g4 + r;
      hout[(size_t)node*HSTR + ct*16 + lq] = f2bf(y);
      float ps = y*as_, pd = y*ad_;
      ps += __shfl_xor(ps,1); ps += __shfl_xor(ps,2); ps += __shfl_xor(ps,4); ps += __shfl_xor(ps,8);
      pd += __shfl_xor(pd,1); pd += __shfl_xor(pd,2); pd += __shfl_xor(pd,4); pd += __shfl_xor(pd,8);
      if (lq==0){
        *(float*)&hout[(size_t)node*HSTR + 64 + 2*ct] = ps;
        ed[(size_t)node*4 + ct] = pd;
      }
    }
  }
}

// ---------------- GAT aggregate: packed-row gather, scalar col loads ----------------
// MODE: 0 = fp32 out only, 1 = bf16 out only, 2 = both
template<int MODE>
__global__ void __launch_bounds__(256) k_aggregate(const unsigned short* __restrict__ h,
                            const float* __restrict__ ed, const int* __restrict__ rowp,
                            const int* __restrict__ col, const float* __restrict__ gb,
                            float* __restrict__ fout, unsigned short* __restrict__ bout){
  int tid = threadIdx.x;
  int n = blockIdx.x*4 + (tid>>6);
  int l = tid&63;
  int q = l>>4;
  int sl = l&15;
  int head = sl>>2;
  float edn = ed[(size_t)n*4 + head];
  float es_self = *(const float*)&h[(size_t)n*HSTR + 64 + 2*head];
  int beg = __builtin_amdgcn_readfirstlane(rowp[n]);
  int end = __builtin_amdgcn_readfirstlane(rowp[n+1]);
  float m = -1e30f, s = 0.f;
  float a0=0.f, a1=0.f, a2=0.f, a3=0.f;
  int i = beg;
  for (; i+8 <= end; i += 8){
    int c0=col[i], c1=col[i+1], c2=col[i+2], c3=col[i+3];
    int c4=col[i+4], c5=col[i+5], c6=col[i+6], c7=col[i+7];
    int t01 = (q&1)? c1 : c0;
    int t23 = (q&1)? c3 : c2;
    int sq0 = (q&2)? t23 : t01;
    int t45 = (q&1)? c5 : c4;
    int t67 = (q&1)? c7 : c6;
    int sq1 = (q&2)? t67 : t45;
    size_t b0r = (size_t)sq0*HSTR, b1r = (size_t)sq1*HSTR;
    ushort4 hv0 = *(const ushort4*)&h[b0r + 4*sl];
    ushort4 hv1 = *(const ushort4*)&h[b1r + 4*sl];
    float e0 = lrelu(*(const float*)&h[b0r + 64 + 2*head] + edn, 0.2f);
    float e1 = lrelu(*(const float*)&h[b1r + 64 + 2*head] + edn, 0.2f);
    float mx = fmaxf(e0, e1);
    if (__any(mx > m + 8.f)){
      float nm = fmaxf(m, mx);
      float c = __expf(m - nm);
      s*=c; a0*=c; a1*=c; a2*=c; a3*=c; m = nm;
    }
    float w0 = __expf(e0 - m);
    float w1 = __expf(e1 - m);
    s += w0 + w1;
    a0 += w0*bf2f(hv0.x) + w1*bf2f(hv1.x);
    a1 += w0*bf2f(hv0.y) + w1*bf2f(hv1.y);
    a2 += w0*bf2f(hv0.z) + w1*bf2f(hv1.z);
    a3 += w0*bf2f(hv0.w) + w1*bf2f(hv1.w);
  }
  if (i < end){
    int last = end-1;
    int i1=(i+1<last)?i+1:last, i2=(i+2<last)?i+2:last, i3=(i+3<last)?i+3:last;
    int i4=(i+4<last)?i+4:last, i5=(i+5<last)?i+5:last, i6=(i+6<last)?i+6:last;
    int c0=col[i], c1=col[i1], c2=col[i2], c3=col[i3];
    int c4=col[i4], c5=col[i5], c6=col[i6], c7=col[last];
    int t01 = (q&1)? c1 : c0;
    int t23 = (q&1)? c3 : c2;
    int sq0 = (q&2)? t23 : t01;
    int t45 = (q&1)? c5 : c4;
    int t67 = (q&1)? c7 : c6;
    int sq1 = (q&2)? t67 : t45;
    bool ac0 = (i + q) < end;
    bool ac1 = (i + 4 + q) < end;
    size_t b0r = (size_t)sq0*HSTR, b1r = (size_t)sq1*HSTR;
    ushort4 hv0 = *(const ushort4*)&h[b0r + 4*sl];
    ushort4 hv1 = *(const ushort4*)&h[b1r + 4*sl];
    float e0 = lrelu(*(const float*)&h[b0r + 64 + 2*head] + edn, 0.2f);
    float e1 = lrelu(*(const float*)&h[b1r + 64 + 2*head] + edn, 0.2f);
    if (!ac0) e0 = -1e30f;
    if (!ac1) e1 = -1e30f;
    float mx = fmaxf(e0, e1);
    if (__any(mx > m + 8.f)){
      float nm = fmaxf(m, mx);
      float c = __expf(m - nm);
      s*=c; a0*=c; a1*=c; a2*=c; a3*=c; m = nm;
    }
    float w0 = ac0 ? __expf(e0 - m) : 0.f;
    float w1 = ac1 ? __expf(e1 - m) : 0.f;
    s += w0 + w1;
    a0 += w0*bf2f(hv0.x) + w1*bf2f(hv1.x);
    a1 += w0*bf2f(hv0.y) + w1*bf2f(hv1.y);
    a2 += w0*bf2f(hv0.z) + w1*bf2f(hv1.z);
    a3 += w0*bf2f(hv0.w) + w1*bf2f(hv1.w);
  }
  #pragma unroll
  for (int off=16; off<=32; off<<=1){
    float m2 = __shfl_xor(m, off);
    float s2 = __shfl_xor(s, off);
    float b0 = __shfl_xor(a0, off);
    float b1 = __shfl_xor(a1, off);
    float b2 = __shfl_xor(a2, off);
    float b3 = __shfl_xor(a3, off);
    float nm = fmaxf(m, m2);
    float c1 = __expf(m - nm), c2 = __expf(m2 - nm);
    s  = s*c1  + s2*c2;
    a0 = a0*c1 + b0*c2;
    a1 = a1*c1 + b1*c2;
    a2 = a2*c1 + b2*c2;
    a3 = a3*c1 + b3*c2;
    m = nm;
  }
  {
    float e_self = lrelu(es_self + edn, 0.2f);
    float nm = fmaxf(m, e_self);
    float c = __expf(m - nm), cs = __expf(e_self - nm);
    ushort4 hs = *(const ushort4*)&h[(size_t)n*HSTR + 4*sl];
    s  = s*c  + cs;
    a0 = a0*c + cs*bf2f(hs.x);
    a1 = a1*c + cs*bf2f(hs.y);
    a2 = a2*c + cs*bf2f(hs.z);
    a3 = a3*c + cs*bf2f(hs.w);
  }
  if (q == 0){
    float inv = 1.f/(s + 1e-16f);
    float4 gv = *(const float4*)&gb[4*sl];
    float o0 = lrelu(a0*inv + gv.x, 0.01f);
    float o1 = lrelu(a1*inv + gv.y, 0.01f);
    float o2 = lrelu(a2*inv + gv.z, 0.01f);
    float o3 = lrelu(a3*inv + gv.w, 0.01f);
    if (MODE==0 || MODE==2){
      *(float4*)(fout + (size_t)n*64 + 4*sl) = make_float4(o0,o1,o2,o3);
    }
    if (MODE==1 || MODE==2){
      ushort4 hv; hv.x=f2bf(o0); hv.y=f2bf(o1); hv.z=f2bf(o2); hv.w=f2bf(o3);
      *(ushort4*)(bout + (size_t)n*64 + 4*sl) = hv;
    }
  }
}

// ---------------- triple linear via MFMA (bf16 inputs), bf16 outputs (scale on slot0) ----------------
__global__ void __launch_bounds__(256) k_qkv3(const unsigned short* __restrict__ in0, const float* __restrict__ W0, const float* __restrict__ b0, unsigned short* __restrict__ o0,
                      const unsigned short* __restrict__ in1, const float* __restrict__ W1, const float* __restrict__ b1, unsigned short* __restrict__ o1,
                      const unsigned short* __restrict__ in2, const float* __restrict__ W2, const float* __restrict__ b2, unsigned short* __restrict__ o2,
                      float scl0){
  __shared__ __align__(16) char Ab[8192];
  __shared__ __align__(16) char Wt[8192];
  int tid = threadIdx.x;
  int n0 = blockIdx.x*64;
  int wave = tid>>6, l=tid&63, lq=l&15, g4=l>>4;
  int nb = wave*16;
  const f32x4 zero = {0.f,0.f,0.f,0.f};
  const unsigned short* ins[3] = {in0, in1, in2};
  const float* Ws[3] = {W0, W1, W2};
  const float* bs[3] = {b0, b1, b2};
  unsigned short* os[3] = {o0, o1, o2};
  const unsigned short* cur = nullptr;
  short8 af[2];
  for (int w=0; w<3; w++){
    bool restage = (ins[w] != cur);
    __syncthreads();
    if (restage){
      cur = ins[w];
      #pragma unroll
      for (int it=0; it<2; it++){
        int idx = tid + it*256;
        int row = idx>>3, gr = idx&7;
        uint4 v = *(const uint4*)(cur + (size_t)(n0+row)*64 + gr*8);
        *(uint4*)(Ab + row*128 + ((gr*16) ^ ((row&7)<<4))) = v;
      }
    }
    #pragma unroll
    for (int it=0; it<4; it++){
      int idx = tid + it*256;
      int k = idx>>4, c4 = (idx&15)<<2;
      float4 v = *(const float4*)(Ws[w] + k*64 + c4);
      float vv[4]={v.x,v.y,v.z,v.w};
      #pragma unroll
      for (int c=0;c<4;c++){
        int colc = c4+c;
        *(unsigned short*)(Wt + colc*128 + ((2*k) ^ ((colc&7)<<4))) = f2bf(vv[c]);
      }
    }
    __syncthreads();
    if (restage){
      #pragma unroll
      for (int s=0;s<2;s++){
        int row = nb+lq;
        af[s] = *(short8*)(Ab + row*128 + (((s*64)+g4*16) ^ ((row&7)<<4)));
      }
    }
    float sc = (w==0) ? scl0 : 1.f;
    #pragma unroll
    for (int ct=0;ct<4;ct++){
      f32x4 acc = zero;
      #pragma unroll
      for (int s=0;s<2;s++){
        int colc = ct*16+lq;
        short8 wf = *(short8*)(Wt + colc*128 + (((s*64)+g4*16) ^ ((colc&7)<<4)));
        acc = __builtin_amdgcn_mfma_f32_16x16x32_bf16(af[s], wf, acc, 0,0,0);
      }
      float bv = bs[w][ct*16+lq];
      #pragma unroll
      for (int r=0;r<4;r++){
        int node = n0 + nb + 4*g4 + r;
        os[w][(size_t)node*64 + ct*16 + lq] = f2bf((acc[r] + bv)*sc);
      }
    }
  }
}

// ---------------- fused FFN via MFMA: out = LN(in + relu(in@W1+b1)@W2+b2) ----------------
__global__ void __launch_bounds__(256) k_ffn(const unsigned short* __restrict__ inb, const float* __restrict__ inf,
                     const float* __restrict__ W1p, const float* __restrict__ b1p,
                     const float* __restrict__ W2p, const float* __restrict__ b2p,
                     const float* __restrict__ g, const float* __restrict__ bl,
                     float* __restrict__ out){
  __shared__ __align__(16) char Ab[8192];
  __shared__ __align__(16) char Wt[8192];
  int tid = threadIdx.x;
  int n0 = blockIdx.x*64;
  int wave = tid>>6, l=tid&63, lq=l&15, g4=l>>4;
  int nb = wave*16;
  const f32x4 zero = {0.f,0.f,0.f,0.f};
  #pragma unroll
  for (int it=0; it<2; it++){
    int idx = tid + it*256;
    int row = idx>>3, gr = idx&7;
    uint4 v = *(const uint4*)(inb + (size_t)(n0+row)*64 + gr*8);
    *(uint4*)(Ab + row*128 + ((gr*16) ^ ((row&7)<<4))) = v;
  }
  #pragma unroll
  for (int it=0; it<4; it++){
    int idx = tid + it*256;
    int k = idx>>4, c4 = (idx&15)<<2;
    float4 v = *(const float4*)(W1p + k*64 + c4);
    float vv[4]={v.x,v.y,v.z,v.w};
    #pragma unroll
    for (int c=0;c<4;c++){
      int colc = c4+c;
      *(unsigned short*)(Wt + colc*128 + ((2*k) ^ ((colc&7)<<4))) = f2bf(vv[c]);
    }
  }
  __syncthreads();
  short8 af[2];
  #pragma unroll
  for (int s=0;s<2;s++){
    int row = nb+lq;
    af[s] = *(short8*)(Ab + row*128 + (((s*64)+g4*16) ^ ((row&7)<<4)));
  }
  #pragma unroll
  for (int ct=0;ct<4;ct++){
    f32x4 acc = zero;
    #pragma unroll
    for (int s=0;s<2;s++){
      int colc = ct*16+lq;
      short8 wf = *(short8*)(Wt + colc*128 + (((s*64)+g4*16) ^ ((colc&7)<<4)));
      acc = __builtin_amdgcn_mfma_f32_16x16x32_bf16(af[s], wf, acc, 0,0,0);
    }
    float bv = b1p[ct*16+lq];
    #pragma unroll
    for (int r=0;r<4;r++){
      int row = nb + 4*g4 + r;
      float y = fmaxf(acc[r] + bv, 0.f);
      *(unsigned short*)(Ab + row*128 + ((2*(ct*16+lq)) ^ ((row&7)<<4))) = f2bf(y);
    }
  }
  __syncthreads();
  #pragma unroll
  for (int it=0; it<4; it++){
    int idx = tid + it*256;
    int k = idx>>4, c4 = (idx&15)<<2;
    float4 v = *(const float4*)(W2p + k*64 + c4);
    float vv[4]={v.x,v.y,v.z,v.w};
    #pragma unroll
    for (int c=0;c<4;c++){
      int colc = c4+c;
      *(unsigned short*)(Wt + colc*128 + ((2*k) ^ ((colc&7)<<4))) = f2bf(vv[c]);
    }
  }
  __syncthreads();
  #pragma unroll
  for (int s=0;s<2;s++){
    int row = nb+lq;
    af[s] = *(short8*)(Ab + row*128 + (((s*64)+g4*16) ^ ((row&7)<<4)));
  }
  float yv[4][4];
  #pragma unroll
  for (int ct=0;ct<4;ct++){
    f32x4 acc = zero;
    #pragma unroll
    for (int s=0;s<2;s++){
      int colc = ct*16+lq;
      short8 wf = *(short8*)(Wt + colc*128 + (((s*64)+g4*16) ^ ((colc&7)<<4)));
      acc = __builtin_amdgcn_mfma_f32_16x16x32_bf16(af[s], wf, acc, 0,0,0);
    }
    float bv = b2p[ct*16+lq];
    #pragma unroll
    for (int r=0;r<4;r++){
      int node = n0 + nb + 4*g4 + r;
      yv[ct][r] = acc[r] + bv + inf[(size_t)node*64 + ct*16 + lq];
    }
  }
  float gg[4], bbl[4];
  #pragma unroll
  for (int ct=0;ct<4;ct++){ gg[ct]=g[ct*16+lq]; bbl[ct]=bl[ct*16+lq]; }
  #pragma unroll
  for (int r=0;r<4;r++){
    int node = n0 + nb + 4*g4 + r;
    float s = (yv[0][r]+yv[1][r]) + (yv[2][r]+yv[3][r]);
    s += __shfl_xor(s,1); s += __shfl_xor(s,2); s += __shfl_xor(s,4); s += __shfl_xor(s,8);
    float mean = s * (1.f/64.f);
    float d[4];
    #pragma unroll
    for (int ct=0;ct<4;ct++) d[ct] = yv[ct][r] - mean;
    float v = (d[0]*d[0]+d[1]*d[1]) + (d[2]*d[2]+d[3]*d[3]);
    v += __shfl_xor(v,1); v += __shfl_xor(v,2); v += __shfl_xor(v,4); v += __shfl_xor(v,8);
    float inv = rsqrtf(v*(1.f/64.f) + 1e-5f);
    #pragma unroll
    for (int ct=0;ct<4;ct++){
      out[(size_t)node*64 + ct*16 + lq] = d[ct]*inv*gg[ct] + bbl[ct];
    }
  }
}

// ---------------- MFMA flash attention + fused out-proj/residual/LN ----------------
// 64-key softmax steps + defer-max; writes fp32 out + bf16 copy.
__global__ void __launch_bounds__(512) k_attn_fused(const unsigned short* __restrict__ Q, const unsigned short* __restrict__ K,
                      const unsigned short* __restrict__ V,
                      const float* __restrict__ Wo, const float* __restrict__ bo,
                      const float* __restrict__ res, const float* __restrict__ g, const float* __restrict__ bl,
                      float* __restrict__ out, unsigned short* __restrict__ outb){
  __shared__ __align__(16) char smem[49152];
  char* Ksm = smem;          // [128 keys][128B both heads], granule XOR swizzle ((row&7)<<4)
  char* Vsm = smem + 16384;  // V^T [64 dims][256B keys], swizzle ((d&7)^(d>>3&7))<<4
  char* Psm = smem + 32768;  // per-wave 2KB: P [16 q][128B keys], swizzle ((lq&7)<<4)

  int bid = blockIdx.x;
  int qq = bid & 3;
  int b  = bid >> 2;
  int tid = threadIdx.x;
  int wave = tid>>6;
  int l = tid & 63;
  int lq = l & 15;
  int g4 = l >> 4;
  int head = wave & 1;
  int qg = wave >> 1;           // 0..3
  const size_t gb = (size_t)b*SEQ*64;
  const int hoff = head*32;
  const f32x4 zero = {0.f,0.f,0.f,0.f};

  int qrow0 = qq*128 + qg*32;
  short8 qf[2];
  f32x4 O[2][2];
  float m_[2], l_[2];
  #pragma unroll
  for (int qt=0; qt<2; qt++){
    qf[qt] = *(const short8*)(Q + gb + (size_t)(qrow0 + qt*16 + lq)*64 + hoff + g4*8);
    O[qt][0] = zero; O[qt][1] = zero;
    m_[qt] = -1e30f; l_[qt] = 0.f;
  }
  char* Pw = Psm + wave*2048;
  int swzp = (lq&7)<<4;
  int d0 = hoff + lq, d1 = hoff + lq + 16;
  int sv0 = (((d0&7) ^ ((d0>>3)&7)) << 4);
  int sv1 = (((d1&7) ^ ((d1>>3)&7)) << 4);

  for (int ph=0; ph<4; ph++){
    __syncthreads();
    #pragma unroll
    for (int it=0; it<2; it++){
      int idx = tid + it*512;
      int row = idx>>3, gr = idx&7;
      uint4 v = *(const uint4*)(K + gb + (size_t)(ph*128 + row)*64 + gr*8);
      *(uint4*)(Ksm + row*128 + ((gr*16) ^ ((row&7)<<4))) = v;
    }
    #pragma unroll
    for (int it=0; it<2; it++){
      int idx = tid + it*512;
      int key = idx>>3, gr = idx&7;
      uint4 vv = *(const uint4*)(V + gb + (size_t)(ph*128 + key)*64 + gr*8);
      const unsigned short* vs = (const unsigned short*)&vv;
      #pragma unroll
      for (int c=0;c<8;c++){
        int d = gr*8 + c;
        int swz = ((c ^ gr) & 7) << 4;
        *(unsigned short*)(Vsm + d*256 + ((key*2) ^ swz)) = vs[c];
      }
    }
    __syncthreads();
    for (int p2=0; p2<2; p2++){
      int rb = p2*64 + lq;
      short8 kf0 = *(short8*)(Ksm + rb*128      + ((hoff*2 + g4*16) ^ ((rb&7)<<4)));
      short8 kf1 = *(short8*)(Ksm + (rb+16)*128 + ((hoff*2 + g4*16) ^ (((rb+16)&7)<<4)));
      short8 kf2 = *(short8*)(Ksm + (rb+32)*128 + ((hoff*2 + g4*16) ^ (((rb+32)&7)<<4)));
      short8 kf3 = *(short8*)(Ksm + (rb+48)*128 + ((hoff*2 + g4*16) ^ (((rb+48)&7)<<4)));
      short8 vt00 = *(short8*)(Vsm + d0*256 + ((p2*128 + g4*16) ^ sv0));
      short8 vt01 = *(short8*)(Vsm + d0*256 + ((p2*128 + 64 + g4*16) ^ sv0));
      short8 vt10 = *(short8*)(Vsm + d1*256 + ((p2*128 + g4*16) ^ sv1));
      short8 vt11 = *(short8*)(Vsm + d1*256 + ((p2*128 + 64 + g4*16) ^ sv1));
      #pragma unroll
      for (int qt=0; qt<2; qt++){
        f32x4 s0 = __builtin_amdgcn_mfma_f32_16x16x32_bf16(kf0, qf[qt], zero, 0,0,0);
        f32x4 s1 = __builtin_amdgcn_mfma_f32_16x16x32_bf16(kf1, qf[qt], zero, 0,0,0);
        f32x4 s2 = __builtin_amdgcn_mfma_f32_16x16x32_bf16(kf2, qf[qt], zero, 0,0,0);
        f32x4 s3 = __builtin_amdgcn_mfma_f32_16x16x32_bf16(kf3, qf[qt], zero, 0,0,0);
        float pmax = fmaxf(
          fmaxf(fmaxf(fmaxf(s0.x,s0.y),fmaxf(s0.z,s0.w)), fmaxf(fmaxf(s1.x,s1.y),fmaxf(s1.z,s1.w))),
          fmaxf(fmaxf(fmaxf(s2.x,s2.y),fmaxf(s2.z,s2.w)), fmaxf(fmaxf(s3.x,s3.y),fmaxf(s3.z,s3.w))));
        pmax = fmaxf(pmax, __shfl_xor(pmax, 16));
        pmax = fmaxf(pmax, __shfl_xor(pmax, 32));
        if (__any(pmax > m_[qt] + 8.f)){
          float mn = fmaxf(m_[qt], pmax);
          float corr = __expf(m_[qt] - mn);
          l_[qt] *= corr;
          O[qt][0] *= corr; O[qt][1] *= corr;
          m_[qt] = mn;
        }
        float mm = m_[qt];
        float e0 = __expf(s0.x - mm), e1 = __expf(s0.y - mm);
        float e2 = __expf(s0.z - mm), e3 = __expf(s0.w - mm);
        float e4 = __expf(s1.x - mm), e5 = __expf(s1.y - mm);
        float e6 = __expf(s1.z - mm), e7 = __expf(s1.w - mm);
        float e8 = __expf(s2.x - mm), e9 = __expf(s2.y - mm);
        float ea = __expf(s2.z - mm), eb = __expf(s2.w - mm);
        float ec = __expf(s3.x - mm), ed_ = __expf(s3.y - mm);
        float ee = __expf(s3.z - mm), ef = __expf(s3.w - mm);
        l_[qt] += (((e0+e1)+(e2+e3)) + ((e4+e5)+(e6+e7)))
                + (((e8+e9)+(ea+eb)) + ((ec+ed_)+(ee+ef)));
        uint2 w0, w1, w2, w3;
        w0.x = (unsigned)f2bf(e0) | ((unsigned)f2bf(e1)<<16);
        w0.y = (unsigned)f2bf(e2) | ((unsigned)f2bf(e3)<<16);
        w1.x = (unsigned)f2bf(e4) | ((unsigned)f2bf(e5)<<16);
        w1.y = (unsigned)f2bf(e6) | ((unsigned)f2bf(e7)<<16);
        w2.x = (unsigned)f2bf(e8) | ((unsigned)f2bf(e9)<<16);
        w2.y = (unsigned)f2bf(ea) | ((unsigned)f2bf(eb)<<16);
        w3.x = (unsigned)f2bf(ec) | ((unsigned)f2bf(ed_)<<16);
        w3.y = (unsigned)f2bf(ee) | ((unsigned)f2bf(ef)<<16);
        *(uint2*)(Pw + lq*128 + ((g4*8) ^ swzp))      = w0;
        *(uint2*)(Pw + lq*128 + ((32 + g4*8) ^ swzp)) = w1;
        *(uint2*)(Pw + lq*128 + ((64 + g4*8) ^ swzp)) = w2;
        *(uint2*)(Pw + lq*128 + ((96 + g4*8) ^ swzp)) = w3;
        short8 pb0 = *(short8*)(Pw + lq*128 + ((g4*16) ^ swzp));
        short8 pb1 = *(short8*)(Pw + lq*128 + ((64 + g4*16) ^ swzp));
        O[qt][0] = __builtin_amdgcn_mfma_f32_16x16x32_bf16(vt00, pb0, O[qt][0], 0,0,0);
        O[qt][0] = __builtin_amdgcn_mfma_f32_16x16x32_bf16(vt01, pb1, O[qt][0], 0,0,0);
        O[qt][1] = __builtin_amdgcn_mfma_f32_16x16x32_bf16(vt10, pb0, O[qt][1], 0,0,0);
        O[qt][1] = __builtin_amdgcn_mfma_f32_16x16x32_bf16(vt11, pb1, O[qt][1], 0,0,0);
      }
    }
  }
  // ---- epilogue: O^T to LDS (bf16 [64][136]), then out-proj + residual + LN ----
  __syncthreads();
  unsigned short* OT = (unsigned short*)smem;           // [64 dims][136 rows]
  float* WoL = (float*)(smem + 17664);                  // [64][64]
  #pragma unroll
  for (int qt=0; qt<2; qt++){
    float lt = l_[qt];
    lt += __shfl_xor(lt, 16);
    lt += __shfl_xor(lt, 32);
    float inv = 1.f/lt;
    int row = qg*32 + qt*16 + lq;
    #pragma unroll
    for (int c=0;c<4;c++){
      OT[(hoff + g4*4 + c)*136 + row]      = f2bf(O[qt][0][c]*inv);
      OT[(hoff + 16 + g4*4 + c)*136 + row] = f2bf(O[qt][1][c]*inv);
    }
  }
  for (int idx=tid; idx<1024; idx+=512){
    int k = idx>>4, jj = (idx&15)<<2;
    *(float4*)&WoL[k*64+jj] = *(const float4*)&Wo[k*64+jj];
  }
  __syncthreads();
  int i = tid>>4, j = tid&15;
  float acc[4][4];
  #pragma unroll
  for (int r=0;r<4;r++){
    #pragma unroll
    for (int c=0;c<4;c++) acc[r][c] = 0.f;
  }
  #pragma unroll 4
  for (int k=0;k<64;k++){
    short4v av = *(short4v*)&OT[k*136 + 4*i];
    float4 bv = *(float4*)&WoL[k*64 + 4*j];
    float b_[4]={bv.x,bv.y,bv.z,bv.w};
    #pragma unroll
    for (int r=0;r<4;r++){
      float a = bf2f((unsigned short)av[r]);
      #pragma unroll
      for (int c=0;c<4;c++) acc[r][c] += a*b_[c];
    }
  }
  float4 bov = *(const float4*)&bo[4*j];
  float4 gv = *(const float4*)&g[4*j];
  float4 blv = *(const float4*)&bl[4*j];
  float bb[4] = {bov.x, bov.y, bov.z, bov.w};
  float gg[4] = {gv.x, gv.y, gv.z, gv.w};
  float bbl[4] = {blv.x, blv.y, blv.z, blv.w};
  #pragma unroll
  for (int r=0;r<4;r++){
    int row = 4*i + r;
    int node = b*SEQ + qq*128 + row;
    float4 rv = *(const float4*)&res[(size_t)node*64 + 4*j];
    float y[4] = {acc[r][0]+bb[0]+rv.x, acc[r][1]+bb[1]+rv.y,
                  acc[r][2]+bb[2]+rv.z, acc[r][3]+bb[3]+rv.w};
    float s = (y[0]+y[1]) + (y[2]+y[3]);
    s += __shfl_xor(s,1); s += __shfl_xor(s,2); s += __shfl_xor(s,4); s += __shfl_xor(s,8);
    float mean = s * (1.f/64.f);
    float d[4] = {y[0]-mean, y[1]-mean, y[2]-mean, y[3]-mean};
    float v = (d[0]*d[0]+d[1]*d[1]) + (d[2]*d[2]+d[3]*d[3]);
    v += __shfl_xor(v,1); v += __shfl_xor(v,2); v += __shfl_xor(v,4); v += __shfl_xor(v,8);
    float inv = rsqrtf(v*(1.f/64.f) + 1e-5f);
    float o0 = d[0]*inv*gg[0]+bbl[0];
    float o1 = d[1]*inv*gg[1]+bbl[1];
    float o2 = d[2]*inv*gg[2]+bbl[2];
    float o3 = d[3]*inv*gg[3]+bbl[3];
    *(float4*)&out[(size_t)node*64 + 4*j] = make_float4(o0,o1,o2,o3);
    ushort4 ob; ob.x=f2bf(o0); ob.y=f2bf(o1); ob.z=f2bf(o2); ob.w=f2bf(o3);
    *(ushort4*)&outb[(size_t)node*64 + 4*j] = ob;
  }
}

// ---------------- mean-pool over 512 nodes + final fc ----------------
__global__ void __launch_bounds__(256) k_pool_fc(const float* __restrict__ t, const float* __restrict__ fcW,
                          const float* __restrict__ fcb, float* __restrict__ out){
  __shared__ float pl[4][64];
  __shared__ float pf[64];
  int b = blockIdx.x;
  int tid = threadIdx.x;
  int j = tid&63, seg = tid>>6;
  const float* basep = t + (size_t)b*SEQ*64;
  float s = 0.f;
  for (int si=seg*128; si<(seg+1)*128; si++) s += basep[(size_t)si*64 + j];
  pl[seg][j] = s;
  __syncthreads();
  if (tid < 64){
    pf[tid] = (pl[0][tid]+pl[1][tid]+pl[2][tid]+pl[3][tid]) * (1.f/512.f);
  }
  __syncthreads();
  if (tid < 64){
    float o = fcb[tid];
    for (int k=0;k<64;k++) o += pf[k]*fcW[k*64+tid];
    out[(size_t)b*64 + tid] = o;
  }
}

extern "C" void kernel_launch(void* const* d_in, const int* in_sizes, int n_in,
                              void* d_out, int out_size, void* d_ws, size_t ws_size,
                              hipStream_t stream) {
  const float* x    = (const float*)d_in[0];
  const int*   ei   = (const int*)d_in[1];      // [2,E]: src row 0, dst row 1
  const float* Wf   = (const float*)d_in[3];
  const float* bf   = (const float*)d_in[4];
  const float* gW0  = (const float*)d_in[5];
  const float* aS0  = (const float*)d_in[6];
  const float* aD0  = (const float*)d_in[7];
  const float* gb0  = (const float*)d_in[8];
  const float* gW   = (const float*)d_in[9];
  const float* aS   = (const float*)d_in[10];
  const float* aD   = (const float*)d_in[11];
  const float* gb   = (const float*)d_in[12];
  const float* sWq  = (const float*)d_in[13];
  const float* sWk  = (const float*)d_in[14];
  const float* sWv  = (const float*)d_in[15];
  const float* sWo  = (const float*)d_in[16];
  const float* cWq  = (const float*)d_in[17];
  const float* cWk  = (const float*)d_in[18];
  const float* cWv  = (const float*)d_in[19];
  const float* cWo  = (const float*)d_in[20];
  const float* sbq  = (const float*)d_in[21];
  const float* sbk  = (const float*)d_in[22];
  const float* sbv  = (const float*)d_in[23];
  const float* sbo  = (const float*)d_in[24];
  const float* cbq  = (const float*)d_in[25];
  const float* cbk  = (const float*)d_in[26];
  const float* cbv  = (const float*)d_in[27];
  const float* cbo  = (const float*)d_in[28];
  const float* ln1g = (const float*)d_in[29];
  const float* ln1b = (const float*)d_in[30];
  const float* ln2g = (const float*)d_in[31];
  const float* ln2b = (const float*)d_in[32];
  const float* ln3g = (const float*)d_in[33];
  const float* ln3b = (const float*)d_in[34];
  const float* ffW1 = (const float*)d_in[35];
  const float* ffb1 = (const float*)d_in[36];
  const float* ffW2 = (const float*)d_in[37];
  const float* ffb2 = (const float*)d_in[38];
  const float* fcW  = (const float*)d_in[39];
  const float* fcb  = (const float*)d_in[40];

  char* ws = (char*)d_ws;
  size_t off = 0;
  auto alloc = [&](size_t bytes) -> void* {
    void* p = ws + off;
    off += (bytes + 255) & ~(size_t)255;
    return p;
  };
  int* deg    = (int*)alloc(NN*sizeof(int));
  int* excl   = (int*)alloc(NN*sizeof(int));
  int* rowp   = (int*)alloc((NN+1)*sizeof(int));
  int* cursor = (int*)alloc(NN*sizeof(int));
  int* col    = (int*)alloc(EE*sizeof(int));
  int* bsums  = (int*)alloc(256*sizeof(int));
  float* ed   = (float*)alloc((size_t)NN*4*sizeof(float));
  unsigned short* Hb   = (unsigned short*)alloc((size_t)NN*HSTR*sizeof(unsigned short));
  unsigned short* Hagg = (unsigned short*)alloc((size_t)NN*64*sizeof(unsigned short));
  unsigned short* Qb  = (unsigned short*)alloc((size_t)NN*64*sizeof(unsigned short));
  unsigned short* Kb  = (unsigned short*)alloc((size_t)NN*64*sizeof(unsigned short));
  unsigned short* Vb  = (unsigned short*)alloc((size_t)NN*64*sizeof(unsigned short));
  unsigned short* B5b = (unsigned short*)alloc((size_t)NN*64*sizeof(unsigned short));
  unsigned short* B2b = (unsigned short*)alloc((size_t)NN*64*sizeof(unsigned short));
  float* B1   = (float*)alloc((size_t)NN*64*sizeof(float));
  float* B2   = (float*)alloc((size_t)NN*64*sizeof(float));
  float* B5   = (float*)alloc((size_t)NN*64*sizeof(float));

  const int* e_src = ei;
  const int* e_dst = ei + EE;

  const float scale = 0.17677669529663687f; // 1/sqrt(32)

  // CSR build
  hipMemsetAsync(deg, 0, NN*sizeof(int), stream);
  k_count<<<EE/256, 256, 0, stream>>>(e_dst, deg);
  k_scan1<<<NN/256, 256, 0, stream>>>(deg, excl, bsums);
  k_scan2<<<1, 256, 0, stream>>>(bsums);
  k_scan3<<<NN/256, 256, 0, stream>>>(excl, bsums, rowp, cursor);
  k_fill<<<EE/256, 256, 0, stream>>>(e_src, e_dst, cursor, col);

  // GAT0: x -> Hb (packed bf16+es) -> Hagg (bf16)
  k_transform0<<<NN/64, 256, 0, stream>>>(x, Wf, bf, gW0, aS0, aD0, Hb, ed);
  k_aggregate<1><<<NN/4, 256, 0, stream>>>(Hb, ed, rowp, col, gb0, nullptr, Hagg);
  // GAT1
  k_transform_bf<<<NN/64, 256, 0, stream>>>(Hagg, gW+0*4096, aS+0*64, aD+0*64, Hb, ed);
  k_aggregate<1><<<NN/4, 256, 0, stream>>>(Hb, ed, rowp, col, gb+0*64, nullptr, Hagg);
  // GAT2
  k_transform_bf<<<NN/64, 256, 0, stream>>>(Hagg, gW+1*4096, aS+1*64, aD+1*64, Hb, ed);
  k_aggregate<1><<<NN/4, 256, 0, stream>>>(Hb, ed, rowp, col, gb+1*64, nullptr, Hagg);
  // GAT3 -> B2 (fp32, residual/mem) + Hagg (bf16 copy, decoder GEMM input)
  k_transform_bf<<<NN/64, 256, 0, stream>>>(Hagg, gW+2*4096, aS+2*64, aD+2*64, Hb, ed);
  k_aggregate<2><<<NN/4, 256, 0, stream>>>(Hb, ed, rowp, col, gb+2*64, B2, Hagg);

  // self-attention: Qb/Kb/Vb from bf16 Hagg; fused attn+proj+res+LN -> B5 (+B5b)
  k_qkv3<<<NN/64, 256, 0, stream>>>(Hagg, sWq, sbq, Qb, Hagg, sWk, sbk, Kb, Hagg, sWv, sbv, Vb, scale);
  k_attn_fused<<<NG*4, 512, 0, stream>>>(Qb, Kb, Vb, sWo, sbo, B2, ln1g, ln1b, B5, B5b);

  // cross-attention: Q from B5b (t1), K/V from Hagg (mem); fused -> B2 (+B2b)
  k_qkv3<<<NN/64, 256, 0, stream>>>(B5b, cWq, cbq, Qb, Hagg, cWk, cbk, Kb, Hagg, cWv, cbv, Vb, scale);
  k_attn_fused<<<NG*4, 512, 0, stream>>>(Qb, Kb, Vb, cWo, cbo, B5, ln2g, ln2b, B2, B2b);

  // fused FFN via MFMA: t3 = LN(t2 + relu(t2@ffW1+ffb1)@ffW2+ffb2) -> B1
  k_ffn<<<NN/64, 256, 0, stream>>>(B2b, B2, ffW1, ffb1, ffW2, ffb2, ln3g, ln3b, B1);

  // pool + fc
  k_pool_fc<<<NG, 256, 0, stream>>>(B1, fcW, fcb, (float*)d_out);
}